// Round 8
// baseline (132.574 us; speedup 1.0000x reference)
//
#include <hip/hip_runtime.h>
#include <hip/hip_bf16.h>
#include <hip/hip_cooperative_groups.h>

#define NN 2048
#define DD 128

namespace cg = cooperative_groups;

typedef __attribute__((ext_vector_type(4))) float f32x4;
typedef __attribute__((ext_vector_type(8))) short short8;
typedef __attribute__((ext_vector_type(2))) unsigned int u32x2;

__device__ __forceinline__ unsigned short f2bf_bits(float f) {
  union { __hip_bfloat16 h; unsigned short s; } u;
  u.h = __float2bfloat16(f);
  return u.s;
}

__device__ __forceinline__ short8 cvt8(f32x4 a, f32x4 b) {
  short8 r;
  r[0] = (short)f2bf_bits(a[0]); r[1] = (short)f2bf_bits(a[1]);
  r[2] = (short)f2bf_bits(a[2]); r[3] = (short)f2bf_bits(a[3]);
  r[4] = (short)f2bf_bits(b[0]); r[5] = (short)f2bf_bits(b[1]);
  r[6] = (short)f2bf_bits(b[2]); r[7] = (short)f2bf_bits(b[3]);
  return r;
}

__device__ __forceinline__ u32x2 pack4(f32x4 v) {
  u32x2 u;
  u[0] = (unsigned)f2bf_bits(v[0]) | ((unsigned)f2bf_bits(v[1]) << 16);
  u[1] = (unsigned)f2bf_bits(v[2]) | ((unsigned)f2bf_bits(v[3]) << 16);
  return u;
}

// ================== single cooperative kernel, 3 phases ==================
// 512 blocks x 512 thr (2 blocks/CU, 16 waves/CU). Block owns batch bb,
// rows m0..m0+31 — SAME rows for degree, y-build, and GEMM output:
//  P1: read own 32 adj rows (f32, from L3/HBM), rowsum -> dnl[32] in LDS.
//      __syncthreads (dnl is block-local; no global dnorm at all).
//  P2: yT[bb][d][n] = bf16(dnl[n-m0] * (x@W)[n][d]) for n in [m0,m0+32).
//      grid.sync (yT is the only cross-block data).
//  P3: r7's k_gemm verbatim (BM=32, A depth-8 regs->LDS ring, B depth-4),
//      epilogue scales by dnl. adj re-read from L3: total adj traffic 2x134MB.
__launch_bounds__(512, 4)
__global__ void k_all(const float* __restrict__ adj, const float* __restrict__ x,
                      const float* __restrict__ W, const float* __restrict__ bias,
                      float* __restrict__ out, short* __restrict__ yT) {
  __shared__ short As[4][2048];  // 16 KB LDS ring for P3
  __shared__ float dnl[32];

  const int t = threadIdx.x;
  const int ln = t & 63;
  const int wv = t >> 6;
  const int l15 = ln & 15, l4 = ln >> 4;

  // XCD-bijective swizzle: XCD x owns batch x (yT slice stays in its L2)
  const int orig = ((blockIdx.x & 7) << 6) | (blockIdx.x >> 3);
  const int bb = orig >> 6;
  const int m0 = (orig & 63) << 5;
  const size_t rowg0 = (size_t)bb * NN + m0;

  // ---- P1: degree of own 32 rows ----
  {
    const int r = (wv << 2) + l4;          // 0..31, 16 lanes per row
    const float* arow = adj + (rowg0 + r) * NN + (l15 << 2);
    float s = 0.f;
#pragma unroll
    for (int rd = 0; rd < 4; ++rd) {
      f32x4 v[8];
#pragma unroll
      for (int j = 0; j < 8; ++j)
        v[j] = *(const f32x4*)(arow + (rd * 8 + j) * 64);
#pragma unroll
      for (int j = 0; j < 8; ++j)
        s += (v[j][0] + v[j][1]) + (v[j][2] + v[j][3]);
    }
    s += __shfl_xor(s, 1); s += __shfl_xor(s, 2);
    s += __shfl_xor(s, 4); s += __shfl_xor(s, 8);
    if (l15 == 0) dnl[r] = rsqrtf(s + 1e-8f);
  }
  __syncthreads();

  // ---- P2: yT[d][n] = bf16(dnl[n]*(x@W)[n][d]) for own 32 n ----
  {
    const int dbase = (wv & 3) << 5;       // 4 d-groups of 32
    const int nh = (wv >> 2) << 4;         // 2 n-halves of 16
    const int nloc = nh + l15;
    const float dn = dnl[nloc];
    const float* xr = x + (rowg0 + nloc) * DD;
    short8 af[2][4];
#pragma unroll
    for (int dt = 0; dt < 2; ++dt)
#pragma unroll
      for (int ks = 0; ks < 4; ++ks) {
        short8 a;
#pragma unroll
        for (int j = 0; j < 8; ++j)
          a[j] = (short)f2bf_bits(W[(size_t)(ks * 32 + l4 * 8 + j) * DD + dbase + dt * 16 + l15]);
        af[dt][ks] = a;
      }
    f32x4 acc2[2]; acc2[0] = (f32x4)0.f; acc2[1] = (f32x4)0.f;
#pragma unroll
    for (int ks = 0; ks < 4; ++ks) {
      f32x4 p = *(const f32x4*)(xr + ks * 32 + l4 * 8);
      f32x4 q = *(const f32x4*)(xr + ks * 32 + l4 * 8 + 4);
      short8 bf = cvt8(p * dn, q * dn);
      acc2[0] = __builtin_amdgcn_mfma_f32_16x16x32_bf16(af[0][ks], bf, acc2[0], 0, 0, 0);
      acc2[1] = __builtin_amdgcn_mfma_f32_16x16x32_bf16(af[1][ks], bf, acc2[1], 0, 0, 0);
    }
    short* yb = yT + (size_t)bb * DD * NN;
#pragma unroll
    for (int dt = 0; dt < 2; ++dt)
#pragma unroll
      for (int rr = 0; rr < 4; ++rr)
        yb[(size_t)(dbase + dt * 16 + l4 * 4 + rr) * NN + m0 + nloc] =
            (short)f2bf_bits(acc2[dt][rr]);
  }

  cg::this_grid().sync();

  // ---- P3: out = (adj_rows @ y) * dnl + b  (r7 k_gemm body) ----
  const float* ablk = adj + rowg0 * NN;
  const int oc = (wv << 4) + l15;
  const int kg8 = l4 << 3;
  const short* ybase = yT + ((size_t)bb * DD + oc) * NN;
  const unsigned srow = (unsigned)t >> 4;
  const unsigned sc4 = ((unsigned)t & 15u) << 2;

  f32x4 acc[2];
  acc[0] = (f32x4)0.0f; acc[1] = (f32x4)0.0f;

  auto loadA = [&](int tile) -> f32x4 {
    return *(const f32x4*)(ablk + (size_t)srow * NN + (tile << 6) + sc4);
  };
  auto loadB = [&](int tile, int ks) -> short8 {
    return *(const short8*)(ybase + (tile << 6) + ks * 32 + kg8);
  };
  auto writeA = [&](f32x4 v, int buf) {
    unsigned byte = (srow << 7) + (sc4 << 1);
    byte ^= (srow & 7u) << 4;
    *(u32x2*)((char*)As + (buf << 12) + byte) = pack4(v);
  };
  auto compute = [&](int buf, short8 b0, short8 b1) {
    const char* base = (const char*)As + (buf << 12);
#pragma unroll
    for (int ks = 0; ks < 2; ++ks) {
      short8 bf = ks ? b1 : b0;
#pragma unroll
      for (int m = 0; m < 2; ++m) {
        unsigned row = (unsigned)(m * 16 + l15);
        unsigned byte = (row << 7) + (unsigned)((ks * 32 + kg8) << 1);
        byte ^= (row & 7u) << 4;
        short8 a = *(const short8*)(base + byte);
        acc[m] = __builtin_amdgcn_mfma_f32_16x16x32_bf16(a, bf, acc[m], 0, 0, 0);
      }
    }
  };

  f32x4 sA0 = loadA(0), sA1 = loadA(1), sA2 = loadA(2), sA3 = loadA(3);
  f32x4 sA4 = loadA(4), sA5 = loadA(5), sA6 = loadA(6), sA7 = loadA(7);
  short8 b0k0 = loadB(0, 0), b0k1 = loadB(0, 1);
  short8 b1k0 = loadB(1, 0), b1k1 = loadB(1, 1);
  short8 b2k0 = loadB(2, 0), b2k1 = loadB(2, 1);
  short8 b3k0 = loadB(3, 0), b3k1 = loadB(3, 1);
  writeA(sA0, 0);
  asm volatile("s_waitcnt lgkmcnt(0)\n\ts_barrier" ::: "memory");

#define GITER(T, SNEW, SWR, BK0, BK1)                                   \
  {                                                                     \
    if ((T) < 24) SNEW = loadA((T) + 8);                                \
    short8 nb0 = BK0, nb1 = BK1;                                        \
    if ((T) < 28) { nb0 = loadB((T) + 4, 0); nb1 = loadB((T) + 4, 1); } \
    writeA(SWR, ((T) + 1) & 3);                                         \
    asm volatile("s_waitcnt lgkmcnt(0)\n\ts_barrier" ::: "memory");     \
    compute((T) & 3, BK0, BK1);                                         \
    BK0 = nb0; BK1 = nb1;                                               \
  }

#pragma unroll 1
  for (int t8 = 0; t8 < 32; t8 += 8) {
    GITER(t8 + 0, sA0, sA1, b0k0, b0k1);
    GITER(t8 + 1, sA1, sA2, b1k0, b1k1);
    GITER(t8 + 2, sA2, sA3, b2k0, b2k1);
    GITER(t8 + 3, sA3, sA4, b3k0, b3k1);
    GITER(t8 + 4, sA4, sA5, b0k0, b0k1);
    GITER(t8 + 5, sA5, sA6, b1k0, b1k1);
    GITER(t8 + 6, sA6, sA7, b2k0, b2k1);
    GITER(t8 + 7, sA7, sA0, b3k0, b3k1);
  }
#undef GITER

  const float bv = bias[oc];
  const int rb = l4 << 2;
#pragma unroll
  for (int m = 0; m < 2; ++m)
#pragma unroll
    for (int rr = 0; rr < 4; ++rr) {
      const int row = m * 16 + rb + rr;
      out[(rowg0 + row) * DD + oc] = acc[m][rr] * dnl[row] + bv;
    }
}

// ===================== fallback (r7 3-kernel, proven 67.9 µs) =====================
__global__ void k_degree(const float* __restrict__ adj, float* __restrict__ dnorm) {
  const int wv = threadIdx.x >> 6;
  const int ln = threadIdx.x & 63;
  const int row = blockIdx.x * 4 + wv;
  const f32x4* rowp = (const f32x4*)(adj + (size_t)row * NN);
  float s = 0.0f;
#pragma unroll
  for (int i = 0; i < 8; ++i) {
    f32x4 v = rowp[i * 64 + ln];
    s += v[0] + v[1] + v[2] + v[3];
  }
#pragma unroll
  for (int off = 32; off >= 1; off >>= 1) s += __shfl_xor(s, off);
  if (ln == 0) dnorm[row] = rsqrtf(s + 1e-8f);
}

__global__ void k_y(const float* __restrict__ x, const float* __restrict__ W,
                    const float* __restrict__ dnorm, short* __restrict__ yT) {
  const int ln = threadIdx.x & 63;
  const int wv = threadIdx.x >> 6;
  const int bb = blockIdx.x >> 5;
  const int n0 = (blockIdx.x & 31) << 6;
  const int l15 = ln & 15, l4 = ln >> 4;
  const int dbase = wv * 32;

  short8 af[2][4];
#pragma unroll
  for (int dt = 0; dt < 2; ++dt)
#pragma unroll
    for (int ks = 0; ks < 4; ++ks) {
      short8 a;
#pragma unroll
      for (int j = 0; j < 8; ++j)
        a[j] = (short)f2bf_bits(W[(size_t)(ks * 32 + l4 * 8 + j) * DD + dbase + dt * 16 + l15]);
      af[dt][ks] = a;
    }

  f32x4 acc[2][4];
#pragma unroll
  for (int dt = 0; dt < 2; ++dt)
#pragma unroll
    for (int nt = 0; nt < 4; ++nt) acc[dt][nt] = (f32x4)0.0f;

  const float* xb = x + (size_t)bb * NN * DD;
  const float* dnb = dnorm + (size_t)bb * NN;
#pragma unroll
  for (int nt = 0; nt < 4; ++nt) {
    const int n = n0 + nt * 16 + l15;
    const float dn = dnb[n];
#pragma unroll
    for (int ks = 0; ks < 4; ++ks) {
      f32x4 p = *(const f32x4*)(xb + (size_t)n * DD + ks * 32 + l4 * 8);
      f32x4 q = *(const f32x4*)(xb + (size_t)n * DD + ks * 32 + l4 * 8 + 4);
      short8 bf = cvt8(p * dn, q * dn);
#pragma unroll
      for (int dt = 0; dt < 2; ++dt)
        acc[dt][nt] = __builtin_amdgcn_mfma_f32_16x16x32_bf16(af[dt][ks], bf, acc[dt][nt], 0, 0, 0);
    }
  }

  short* yb = yT + (size_t)bb * DD * NN;
#pragma unroll
  for (int dt = 0; dt < 2; ++dt)
#pragma unroll
    for (int nt = 0; nt < 4; ++nt)
#pragma unroll
      for (int rr = 0; rr < 4; ++rr) {
        int d = dbase + dt * 16 + l4 * 4 + rr;
        yb[(size_t)d * NN + n0 + nt * 16 + l15] = (short)f2bf_bits(acc[dt][nt][rr]);
      }
}

__launch_bounds__(512, 4)
__global__ void k_gemm(const float* __restrict__ adj, const short* __restrict__ yT,
                       const float* __restrict__ dnorm, const float* __restrict__ bias,
                       float* __restrict__ out) {
  __shared__ short As[4][2048];

  const int t = threadIdx.x;
  const int ln = t & 63;
  const int wv = t >> 6;
  const int orig = ((blockIdx.x & 7) << 6) | (blockIdx.x >> 3);
  const int bb = orig >> 6;
  const int m0 = (orig & 63) << 5;

  const float* ablk = adj + ((size_t)bb * NN + m0) * NN;
  const int oc = (wv << 4) + (ln & 15);
  const int kg8 = (ln >> 4) << 3;
  const short* ybase = yT + ((size_t)bb * DD + oc) * NN;

  const unsigned srow = (unsigned)t >> 4;
  const unsigned sc4 = ((unsigned)t & 15u) << 2;

  f32x4 acc[2];
  acc[0] = (f32x4)0.0f; acc[1] = (f32x4)0.0f;

  auto loadA = [&](int tile) -> f32x4 {
    return *(const f32x4*)(ablk + (size_t)srow * NN + (tile << 6) + sc4);
  };
  auto loadB = [&](int tile, int ks) -> short8 {
    return *(const short8*)(ybase + (tile << 6) + ks * 32 + kg8);
  };
  auto writeA = [&](f32x4 v, int buf) {
    unsigned byte = (srow << 7) + (sc4 << 1);
    byte ^= (srow & 7u) << 4;
    *(u32x2*)((char*)As + (buf << 12) + byte) = pack4(v);
  };
  auto compute = [&](int buf, short8 b0, short8 b1) {
    const char* base = (const char*)As + (buf << 12);
#pragma unroll
    for (int ks = 0; ks < 2; ++ks) {
      short8 bf = ks ? b1 : b0;
#pragma unroll
      for (int m = 0; m < 2; ++m) {
        unsigned row = (unsigned)(m * 16 + (ln & 15));
        unsigned byte = (row << 7) + (unsigned)((ks * 32 + kg8) << 1);
        byte ^= (row & 7u) << 4;
        short8 a = *(const short8*)(base + byte);
        acc[m] = __builtin_amdgcn_mfma_f32_16x16x32_bf16(a, bf, acc[m], 0, 0, 0);
      }
    }
  };

  f32x4 sA0 = loadA(0), sA1 = loadA(1), sA2 = loadA(2), sA3 = loadA(3);
  f32x4 sA4 = loadA(4), sA5 = loadA(5), sA6 = loadA(6), sA7 = loadA(7);
  short8 b0k0 = loadB(0, 0), b0k1 = loadB(0, 1);
  short8 b1k0 = loadB(1, 0), b1k1 = loadB(1, 1);
  short8 b2k0 = loadB(2, 0), b2k1 = loadB(2, 1);
  short8 b3k0 = loadB(3, 0), b3k1 = loadB(3, 1);
  writeA(sA0, 0);
  asm volatile("s_waitcnt lgkmcnt(0)\n\ts_barrier" ::: "memory");

#define GITER(T, SNEW, SWR, BK0, BK1)                                   \
  {                                                                     \
    if ((T) < 24) SNEW = loadA((T) + 8);                                \
    short8 nb0 = BK0, nb1 = BK1;                                        \
    if ((T) < 28) { nb0 = loadB((T) + 4, 0); nb1 = loadB((T) + 4, 1); } \
    writeA(SWR, ((T) + 1) & 3);                                         \
    asm volatile("s_waitcnt lgkmcnt(0)\n\ts_barrier" ::: "memory");     \
    compute((T) & 3, BK0, BK1);                                         \
    BK0 = nb0; BK1 = nb1;                                               \
  }

#pragma unroll 1
  for (int t8 = 0; t8 < 32; t8 += 8) {
    GITER(t8 + 0, sA0, sA1, b0k0, b0k1);
    GITER(t8 + 1, sA1, sA2, b1k0, b1k1);
    GITER(t8 + 2, sA2, sA3, b2k0, b2k1);
    GITER(t8 + 3, sA3, sA4, b3k0, b3k1);
    GITER(t8 + 4, sA4, sA5, b0k0, b0k1);
    GITER(t8 + 5, sA5, sA6, b1k0, b1k1);
    GITER(t8 + 6, sA6, sA7, b2k0, b2k1);
    GITER(t8 + 7, sA7, sA0, b3k0, b3k1);
  }
#undef GITER

  const float bv = bias[oc];
  const int rbase = (ln >> 4) << 2;
#pragma unroll
  for (int m = 0; m < 2; ++m) {
    f32x4 dn = *(const f32x4*)(dnorm + (size_t)bb * NN + m0 + m * 16 + rbase);
#pragma unroll
    for (int rr = 0; rr < 4; ++rr)
      out[(size_t)(bb * NN + m0 + m * 16 + rbase + rr) * DD + oc] = acc[m][rr] * dn[rr] + bv;
  }
}

extern "C" void kernel_launch(void* const* d_in, const int* in_sizes, int n_in,
                              void* d_out, int out_size, void* d_ws, size_t ws_size,
                              hipStream_t stream) {
  (void)in_sizes; (void)n_in; (void)out_size; (void)ws_size;
  const float* x = (const float*)d_in[0];
  const float* adj = (const float*)d_in[1];
  const float* W = (const float*)d_in[2];
  const float* bias = (const float*)d_in[3];
  float* out = (float*)d_out;

  char* ws = (char*)d_ws;
  float* dnorm = (float*)ws;             // 64 KB (fallback only)
  short* yT = (short*)(ws + (1 << 16));  // 4 MB

  void* args[] = {(void*)&adj, (void*)&x, (void*)&W, (void*)&bias,
                  (void*)&out, (void*)&yT};
  hipError_t e = hipLaunchCooperativeKernel((const void*)k_all, dim3(512),
                                            dim3(512), args, 0, stream);
  if (e != hipSuccess) {
    (void)hipGetLastError();  // clear sticky error, take proven 3-kernel path
    k_degree<<<4096, 256, 0, stream>>>(adj, dnorm);
    k_y<<<256, 256, 0, stream>>>(x, W, dnorm, yT);
    k_gemm<<<512, 512, 0, stream>>>(adj, yT, dnorm, bias, out);
  }
}

// Round 9
// 118.816 us; speedup vs baseline: 1.1158x; 1.1158x over previous
//
#include <hip/hip_runtime.h>
#include <hip/hip_bf16.h>

#define NN 2048
#define DD 128

typedef __attribute__((ext_vector_type(4))) float f32x4;
typedef __attribute__((ext_vector_type(8))) short short8;

__device__ __forceinline__ unsigned short f2bf_bits(float f) {
  union { __hip_bfloat16 h; unsigned short s; } u;
  u.h = __float2bfloat16(f);
  return u.s;
}

__device__ __forceinline__ short8 cvt8(f32x4 a, f32x4 b) {
  short8 r;
  r[0] = (short)f2bf_bits(a[0]); r[1] = (short)f2bf_bits(a[1]);
  r[2] = (short)f2bf_bits(a[2]); r[3] = (short)f2bf_bits(a[3]);
  r[4] = (short)f2bf_bits(b[0]); r[5] = (short)f2bf_bits(b[1]);
  r[6] = (short)f2bf_bits(b[2]); r[7] = (short)f2bf_bits(b[3]);
  return r;
}

// ---------- K1: dnorm = rsqrt(rowsum(adj)+1e-8) ----------
__global__ void k_degree(const float* __restrict__ adj, float* __restrict__ dnorm) {
  const int wv = threadIdx.x >> 6;
  const int ln = threadIdx.x & 63;
  const int row = blockIdx.x * 4 + wv;
  const f32x4* rowp = (const f32x4*)(adj + (size_t)row * NN);
  float s = 0.0f;
#pragma unroll
  for (int i = 0; i < 8; ++i) {
    f32x4 v = rowp[i * 64 + ln];
    s += v[0] + v[1] + v[2] + v[3];
  }
#pragma unroll
  for (int off = 32; off >= 1; off >>= 1) s += __shfl_xor(s, off);
  if (ln == 0) dnorm[row] = rsqrtf(s + 1e-8f);
}

// ---------- K2: yT[b][d][n] = bf16(dnorm[n] * (x@W)[n][d]) ----------
__global__ void k_y(const float* __restrict__ x, const float* __restrict__ W,
                    const float* __restrict__ dnorm, short* __restrict__ yT) {
  const int ln = threadIdx.x & 63;
  const int wv = threadIdx.x >> 6;
  const int bb = blockIdx.x >> 5;
  const int n0 = (blockIdx.x & 31) << 6;
  const int l15 = ln & 15, l4 = ln >> 4;
  const int dbase = wv * 32;

  short8 af[2][4];
#pragma unroll
  for (int dt = 0; dt < 2; ++dt)
#pragma unroll
    for (int ks = 0; ks < 4; ++ks) {
      short8 a;
#pragma unroll
      for (int j = 0; j < 8; ++j)
        a[j] = (short)f2bf_bits(W[(size_t)(ks * 32 + l4 * 8 + j) * DD + dbase + dt * 16 + l15]);
      af[dt][ks] = a;
    }

  f32x4 acc[2][4];
#pragma unroll
  for (int dt = 0; dt < 2; ++dt)
#pragma unroll
    for (int nt = 0; nt < 4; ++nt) acc[dt][nt] = (f32x4)0.0f;

  const float* xb = x + (size_t)bb * NN * DD;
  const float* dnb = dnorm + (size_t)bb * NN;
#pragma unroll
  for (int nt = 0; nt < 4; ++nt) {
    const int n = n0 + nt * 16 + l15;
    const float dn = dnb[n];
#pragma unroll
    for (int ks = 0; ks < 4; ++ks) {
      f32x4 p = *(const f32x4*)(xb + (size_t)n * DD + ks * 32 + l4 * 8);
      f32x4 q = *(const f32x4*)(xb + (size_t)n * DD + ks * 32 + l4 * 8 + 4);
      short8 bf = cvt8(p * dn, q * dn);
#pragma unroll
      for (int dt = 0; dt < 2; ++dt)
        acc[dt][nt] = __builtin_amdgcn_mfma_f32_16x16x32_bf16(af[dt][ks], bf, acc[dt][nt], 0, 0, 0);
    }
  }

  short* yb = yT + (size_t)bb * DD * NN;
#pragma unroll
  for (int dt = 0; dt < 2; ++dt)
#pragma unroll
    for (int nt = 0; nt < 4; ++nt)
#pragma unroll
      for (int rr = 0; rr < 4; ++rr) {
        int d = dbase + dt * 16 + l4 * 4 + rr;
        yb[(size_t)d * NN + n0 + nt * 16 + l15] = (short)f2bf_bits(acc[dt][nt][rr]);
      }
}

// ---------- K3: wave-private GEMM — NO LDS, NO barriers ----------
// 512 blocks x 256 thr (2048 waves, 8 waves/CU). Each wave owns 16 rows x 64 d:
// A-frag straight from global (f32->bf16 in reg), B-frag from L2-resident yT
// slice. Depth-4 A / depth-2 B static register pipeline. Waves free-run at
// memory BW instead of the barrier cadence (r2/r3/r7 showed barrier-pipelined
// GEMM caps at ~3 TB/s vs ~6 for free streams).
__launch_bounds__(256, 2)
__global__ void k_wgemm(const float* __restrict__ adj, const short* __restrict__ yT,
                        const float* __restrict__ dnorm, const float* __restrict__ bias,
                        float* __restrict__ out) {
  const int ln = threadIdx.x & 63;
  const int wv = threadIdx.x >> 6;           // 0..3
  const int l15 = ln & 15, l4 = ln >> 4;
  // XCD-bijective swizzle: batch = bid&7 -> XCD-local yT slice
  const int orig = ((blockIdx.x & 7) << 6) | (blockIdx.x >> 3);
  const int bb = orig >> 6;
  const int gw = ((orig & 63) << 2) | wv;    // 0..255 within batch
  const int rowtile = gw >> 1;               // 0..127
  const int d0 = (gw & 1) << 6;              // 0 or 64
  const size_t m0g = (size_t)bb * NN + ((size_t)rowtile << 4);

  const float* arow = adj + (m0g + l15) * NN + (l4 << 3);
  const short* ybb = yT + (size_t)bb * DD * NN + (l4 << 3);
  const short* br0 = ybb + (size_t)(d0 + l15) * NN;
  const short* br1 = ybb + (size_t)(d0 + 16 + l15) * NN;
  const short* br2 = ybb + (size_t)(d0 + 32 + l15) * NN;
  const short* br3 = ybb + (size_t)(d0 + 48 + l15) * NN;

  f32x4 acc0 = (f32x4)0.f, acc1 = (f32x4)0.f, acc2 = (f32x4)0.f, acc3 = (f32x4)0.f;

  // prologue: A k-steps 0..3, B k-steps 0 (even slot) & 1 (odd slot)
  f32x4 a0L = *(const f32x4*)(arow + 0 * 32), a0H = *(const f32x4*)(arow + 0 * 32 + 4);
  f32x4 a1L = *(const f32x4*)(arow + 1 * 32), a1H = *(const f32x4*)(arow + 1 * 32 + 4);
  f32x4 a2L = *(const f32x4*)(arow + 2 * 32), a2H = *(const f32x4*)(arow + 2 * 32 + 4);
  f32x4 a3L = *(const f32x4*)(arow + 3 * 32), a3H = *(const f32x4*)(arow + 3 * 32 + 4);
  short8 e0 = *(const short8*)(br0 + 0), e1 = *(const short8*)(br1 + 0);
  short8 e2 = *(const short8*)(br2 + 0), e3 = *(const short8*)(br3 + 0);
  short8 o0 = *(const short8*)(br0 + 32), o1 = *(const short8*)(br1 + 32);
  short8 o2 = *(const short8*)(br2 + 32), o3 = *(const short8*)(br3 + 32);

  // step J: consume A slot J&3 (holds kt=J), B slot J&1 (holds kt=J);
  // reload A slot <- kt=J+4, B slot <- kt=J+2. DOA/DOB are literal flags.
#define KS(J, AL, AH, B0_, B1_, B2_, B3_, DOA, DOB)                          \
  {                                                                          \
    short8 af = cvt8(AL, AH);                                                \
    acc0 = __builtin_amdgcn_mfma_f32_16x16x32_bf16(af, B0_, acc0, 0, 0, 0);  \
    acc1 = __builtin_amdgcn_mfma_f32_16x16x32_bf16(af, B1_, acc1, 0, 0, 0);  \
    acc2 = __builtin_amdgcn_mfma_f32_16x16x32_bf16(af, B2_, acc2, 0, 0, 0);  \
    acc3 = __builtin_amdgcn_mfma_f32_16x16x32_bf16(af, B3_, acc3, 0, 0, 0);  \
    if (DOA) {                                                               \
      AL = *(const f32x4*)(arow + ((J) + 4) * 32);                           \
      AH = *(const f32x4*)(arow + ((J) + 4) * 32 + 4);                       \
    }                                                                        \
    if (DOB) {                                                               \
      B0_ = *(const short8*)(br0 + ((J) + 2) * 32);                          \
      B1_ = *(const short8*)(br1 + ((J) + 2) * 32);                          \
      B2_ = *(const short8*)(br2 + ((J) + 2) * 32);                          \
      B3_ = *(const short8*)(br3 + ((J) + 2) * 32);                          \
    }                                                                        \
  }

#pragma unroll 1
  for (int j = 0; j < 60; j += 4) {
    KS(j + 0, a0L, a0H, e0, e1, e2, e3, 1, 1);
    KS(j + 1, a1L, a1H, o0, o1, o2, o3, 1, 1);
    KS(j + 2, a2L, a2H, e0, e1, e2, e3, 1, 1);
    KS(j + 3, a3L, a3H, o0, o1, o2, o3, 1, 1);
  }
  KS(60, a0L, a0H, e0, e1, e2, e3, 0, 1);
  KS(61, a1L, a1H, o0, o1, o2, o3, 0, 1);
  KS(62, a2L, a2H, e0, e1, e2, e3, 0, 0);
  KS(63, a3L, a3H, o0, o1, o2, o3, 0, 0);
#undef KS

  // epilogue: out = dnorm_row * acc + bias
  f32x4 dn4 = *(const f32x4*)(dnorm + m0g + (l4 << 2));
  const float bv0 = bias[d0 + l15];
  const float bv1 = bias[d0 + 16 + l15];
  const float bv2 = bias[d0 + 32 + l15];
  const float bv3 = bias[d0 + 48 + l15];
#pragma unroll
  for (int rr = 0; rr < 4; ++rr) {
    const size_t base = (m0g + (l4 << 2) + rr) * DD + d0 + l15;
    out[base] = acc0[rr] * dn4[rr] + bv0;
    out[base + 16] = acc1[rr] * dn4[rr] + bv1;
    out[base + 32] = acc2[rr] * dn4[rr] + bv2;
    out[base + 48] = acc3[rr] * dn4[rr] + bv3;
  }
}

extern "C" void kernel_launch(void* const* d_in, const int* in_sizes, int n_in,
                              void* d_out, int out_size, void* d_ws, size_t ws_size,
                              hipStream_t stream) {
  (void)in_sizes; (void)n_in; (void)out_size; (void)ws_size;
  const float* x = (const float*)d_in[0];
  const float* adj = (const float*)d_in[1];
  const float* W = (const float*)d_in[2];
  const float* bias = (const float*)d_in[3];
  float* out = (float*)d_out;

  char* ws = (char*)d_ws;
  float* dnorm = (float*)ws;             // 64 KB
  short* yT = (short*)(ws + (1 << 16));  // 4 MB

  k_degree<<<4096, 256, 0, stream>>>(adj, dnorm);
  k_y<<<256, 256, 0, stream>>>(x, W, dnorm, yT);
  k_wgemm<<<512, 256, 0, stream>>>(adj, yT, dnorm, bias, out);
}

// Round 10
// 95.504 us; speedup vs baseline: 1.3882x; 1.2441x over previous
//
#include <hip/hip_runtime.h>
#include <hip/hip_bf16.h>

#define NN 2048
#define DD 128

typedef __attribute__((ext_vector_type(4))) float f32x4;
typedef __attribute__((ext_vector_type(8))) short short8;
typedef __attribute__((ext_vector_type(2))) unsigned int u32x2;

__device__ __forceinline__ unsigned short f2bf_bits(float f) {
  union { __hip_bfloat16 h; unsigned short s; } u;
  u.h = __float2bfloat16(f);
  return u.s;
}

__device__ __forceinline__ short8 cvt8(f32x4 a, f32x4 b) {
  short8 r;
  r[0] = (short)f2bf_bits(a[0]); r[1] = (short)f2bf_bits(a[1]);
  r[2] = (short)f2bf_bits(a[2]); r[3] = (short)f2bf_bits(a[3]);
  r[4] = (short)f2bf_bits(b[0]); r[5] = (short)f2bf_bits(b[1]);
  r[6] = (short)f2bf_bits(b[2]); r[7] = (short)f2bf_bits(b[3]);
  return r;
}

__device__ __forceinline__ u32x2 pack4(f32x4 v) {
  u32x2 u;
  u[0] = (unsigned)f2bf_bits(v[0]) | ((unsigned)f2bf_bits(v[1]) << 16);
  u[1] = (unsigned)f2bf_bits(v[2]) | ((unsigned)f2bf_bits(v[3]) << 16);
  return u;
}

// ---------- K1: dnorm = rsqrt(rowsum(adj)+1e-8) ----------
__global__ void k_degree(const float* __restrict__ adj, float* __restrict__ dnorm) {
  const int wv = threadIdx.x >> 6;
  const int ln = threadIdx.x & 63;
  const int row = blockIdx.x * 4 + wv;
  const f32x4* rowp = (const f32x4*)(adj + (size_t)row * NN);
  float s = 0.0f;
#pragma unroll
  for (int i = 0; i < 8; ++i) {
    f32x4 v = rowp[i * 64 + ln];
    s += v[0] + v[1] + v[2] + v[3];
  }
#pragma unroll
  for (int off = 32; off >= 1; off >>= 1) s += __shfl_xor(s, off);
  if (ln == 0) dnorm[row] = rsqrtf(s + 1e-8f);
}

// ---------- K2: yT[b][d][n] = bf16(dnorm[n] * (x@W)[n][d]) ----------
__global__ void k_y(const float* __restrict__ x, const float* __restrict__ W,
                    const float* __restrict__ dnorm, short* __restrict__ yT) {
  const int ln = threadIdx.x & 63;
  const int wv = threadIdx.x >> 6;
  const int bb = blockIdx.x >> 5;
  const int n0 = (blockIdx.x & 31) << 6;
  const int l15 = ln & 15, l4 = ln >> 4;
  const int dbase = wv * 32;

  short8 af[2][4];
#pragma unroll
  for (int dt = 0; dt < 2; ++dt)
#pragma unroll
    for (int ks = 0; ks < 4; ++ks) {
      short8 a;
#pragma unroll
      for (int j = 0; j < 8; ++j)
        a[j] = (short)f2bf_bits(W[(size_t)(ks * 32 + l4 * 8 + j) * DD + dbase + dt * 16 + l15]);
      af[dt][ks] = a;
    }

  f32x4 acc[2][4];
#pragma unroll
  for (int dt = 0; dt < 2; ++dt)
#pragma unroll
    for (int nt = 0; nt < 4; ++nt) acc[dt][nt] = (f32x4)0.0f;

  const float* xb = x + (size_t)bb * NN * DD;
  const float* dnb = dnorm + (size_t)bb * NN;
#pragma unroll
  for (int nt = 0; nt < 4; ++nt) {
    const int n = n0 + nt * 16 + l15;
    const float dn = dnb[n];
#pragma unroll
    for (int ks = 0; ks < 4; ++ks) {
      f32x4 p = *(const f32x4*)(xb + (size_t)n * DD + ks * 32 + l4 * 8);
      f32x4 q = *(const f32x4*)(xb + (size_t)n * DD + ks * 32 + l4 * 8 + 4);
      short8 bf = cvt8(p * dn, q * dn);
#pragma unroll
      for (int dt = 0; dt < 2; ++dt)
        acc[dt][nt] = __builtin_amdgcn_mfma_f32_16x16x32_bf16(af[dt][ks], bf, acc[dt][nt], 0, 0, 0);
    }
  }

  short* yb = yT + (size_t)bb * DD * NN;
#pragma unroll
  for (int dt = 0; dt < 2; ++dt)
#pragma unroll
    for (int nt = 0; nt < 4; ++nt)
#pragma unroll
      for (int rr = 0; rr < 4; ++rr) {
        int d = dbase + dt * 16 + l4 * 4 + rr;
        yb[(size_t)d * NN + n0 + nt * 16 + l15] = (short)f2bf_bits(acc[dt][nt][rr]);
      }
}

// ---------- K3: BM=16 GEMM, 4 independent blocks/CU ----------
// 1024 blocks x 256 thr (4 blocks/CU, 16 waves/CU). Block owns 16 rows; each
// of 4 waves owns 32 d-cols (2 acc tiles). One f32 tile (16x64) staged per
// iter by all 256 thr; ring-4 LDS; depth-4 A regs, depth-1 B. Barrier per
// iter is block-local — 4 unsynced blocks/CU cover each other's stalls.
__launch_bounds__(256, 4)
__global__ void k_gemm16(const float* __restrict__ adj, const short* __restrict__ yT,
                         const float* __restrict__ dnorm, const float* __restrict__ bias,
                         float* __restrict__ out) {
  __shared__ short As[4][1024];  // 4 x 2 KB [16 rows][64 k] bf16, XOR-swizzled

  const int t = threadIdx.x;
  const int ln = t & 63;
  const int wv = t >> 6;                 // 0..3
  const int l15 = ln & 15, l4 = ln >> 4; // l4 in 0..3
  // XCD-bijective swizzle (nwg=1024, 1024%8==0): XCD x gets batch x
  const int orig = ((blockIdx.x & 7) << 7) | (blockIdx.x >> 3);
  const int bb = orig >> 7;
  const int m0 = (orig & 127) << 4;
  const size_t m0g = (size_t)bb * NN + m0;

  const float* ablk = adj + m0g * NN;
  const int dbase = wv << 5;             // wave's 32 d-cols
  const short* yb0 = yT + ((size_t)bb * DD + dbase + l15) * NN + (l4 << 3);
  const short* yb1 = yT + ((size_t)bb * DD + dbase + 16 + l15) * NN + (l4 << 3);

  const int srow = t >> 4;               // staging row 0..15
  const int sc4 = (t & 15) << 2;         // staging f32 col

  f32x4 acc0 = (f32x4)0.f, acc1 = (f32x4)0.f;

  auto loadA = [&](int kt) -> f32x4 {
    return *(const f32x4*)(ablk + (size_t)srow * NN + (kt << 6) + sc4);
  };
  auto writeA = [&](f32x4 v, int buf) {
    unsigned byte = ((unsigned)srow << 7) + ((unsigned)sc4 << 1);
    byte ^= ((unsigned)srow & 7u) << 4;          // closed within 128B row
    *(u32x2*)((char*)As + (buf << 11) + byte) = pack4(v);
  };
  auto compute = [&](int buf, short8 b00, short8 b01, short8 b10, short8 b11) {
    const char* base = (const char*)As + (buf << 11);
    unsigned b0 = ((unsigned)l15 << 7) + ((unsigned)l4 << 4);
    unsigned sw = ((unsigned)l15 & 7u) << 4;
    short8 a0 = *(const short8*)(base + (b0 ^ sw));           // ks=0
    short8 a1 = *(const short8*)(base + ((b0 + 64) ^ sw));    // ks=1
    acc0 = __builtin_amdgcn_mfma_f32_16x16x32_bf16(a0, b00, acc0, 0, 0, 0);
    acc0 = __builtin_amdgcn_mfma_f32_16x16x32_bf16(a1, b01, acc0, 0, 0, 0);
    acc1 = __builtin_amdgcn_mfma_f32_16x16x32_bf16(a0, b10, acc1, 0, 0, 0);
    acc1 = __builtin_amdgcn_mfma_f32_16x16x32_bf16(a1, b11, acc1, 0, 0, 0);
  };

  // prologue: A tiles 0..3 in regs, B tile 0 in regs, tile 0 -> buf0
  f32x4 s0 = loadA(0), s1 = loadA(1), s2 = loadA(2), s3 = loadA(3);
  short8 c00 = *(const short8*)(yb0 + 0), c01 = *(const short8*)(yb0 + 32);
  short8 c10 = *(const short8*)(yb1 + 0), c11 = *(const short8*)(yb1 + 32);
  writeA(s0, 0);
  asm volatile("s_waitcnt lgkmcnt(0)\n\ts_barrier" ::: "memory");

  // GITER(T): slot T&3 <- tile T+4; B temps <- tile T+1; write slot (T+1)&3
  // (tile T+1) to buf (T+1)&3; barrier; compute tile T; commit B.
#define GITER(T, SNEW, SWR)                                             \
  {                                                                     \
    if ((T) < 28) SNEW = loadA((T) + 4);                                \
    short8 n00 = c00, n01 = c01, n10 = c10, n11 = c11;                  \
    if ((T) < 31) {                                                     \
      n00 = *(const short8*)(yb0 + ((T) + 1) * 64);                     \
      n01 = *(const short8*)(yb0 + ((T) + 1) * 64 + 32);                \
      n10 = *(const short8*)(yb1 + ((T) + 1) * 64);                     \
      n11 = *(const short8*)(yb1 + ((T) + 1) * 64 + 32);                \
      writeA(SWR, ((T) + 1) & 3);                                       \
    }                                                                   \
    asm volatile("s_waitcnt lgkmcnt(0)\n\ts_barrier" ::: "memory");     \
    compute((T) & 3, c00, c01, c10, c11);                               \
    c00 = n00; c01 = n01; c10 = n10; c11 = n11;                         \
  }

#pragma unroll 1
  for (int t4 = 0; t4 < 32; t4 += 4) {
    GITER(t4 + 0, s0, s1);
    GITER(t4 + 1, s1, s2);
    GITER(t4 + 2, s2, s3);
    GITER(t4 + 3, s3, s0);
  }
#undef GITER

  // epilogue: out = dnorm_row * acc + bias
  f32x4 dn4 = *(const f32x4*)(dnorm + m0g + (l4 << 2));
  const float bv0 = bias[dbase + l15];
  const float bv1 = bias[dbase + 16 + l15];
#pragma unroll
  for (int rr = 0; rr < 4; ++rr) {
    const size_t base = (m0g + (l4 << 2) + rr) * DD + dbase + l15;
    out[base] = acc0[rr] * dn4[rr] + bv0;
    out[base + 16] = acc1[rr] * dn4[rr] + bv1;
  }
}

extern "C" void kernel_launch(void* const* d_in, const int* in_sizes, int n_in,
                              void* d_out, int out_size, void* d_ws, size_t ws_size,
                              hipStream_t stream) {
  (void)in_sizes; (void)n_in; (void)out_size; (void)ws_size;
  const float* x = (const float*)d_in[0];
  const float* adj = (const float*)d_in[1];
  const float* W = (const float*)d_in[2];
  const float* bias = (const float*)d_in[3];
  float* out = (float*)d_out;

  char* ws = (char*)d_ws;
  float* dnorm = (float*)ws;             // 64 KB
  short* yT = (short*)(ws + (1 << 16));  // 4 MB

  k_degree<<<4096, 256, 0, stream>>>(adj, dnorm);
  k_y<<<256, 256, 0, stream>>>(x, W, dnorm, yT);
  k_gemm16<<<1024, 256, 0, stream>>>(adj, yT, dnorm, bias, out);
}

// Round 11
// 77.210 us; speedup vs baseline: 1.7171x; 1.2369x over previous
//
#include <hip/hip_runtime.h>
#include <hip/hip_bf16.h>

#define NN 2048
#define DD 128

typedef __attribute__((ext_vector_type(4))) float f32x4;
typedef __attribute__((ext_vector_type(8))) short short8;
typedef __attribute__((ext_vector_type(2))) unsigned int u32x2;

__device__ __forceinline__ unsigned short f2bf_bits(float f) {
  union { __hip_bfloat16 h; unsigned short s; } u;
  u.h = __float2bfloat16(f);
  return u.s;
}

__device__ __forceinline__ short8 cvt8(f32x4 a, f32x4 b) {
  short8 r;
  r[0] = (short)f2bf_bits(a[0]); r[1] = (short)f2bf_bits(a[1]);
  r[2] = (short)f2bf_bits(a[2]); r[3] = (short)f2bf_bits(a[3]);
  r[4] = (short)f2bf_bits(b[0]); r[5] = (short)f2bf_bits(b[1]);
  r[6] = (short)f2bf_bits(b[2]); r[7] = (short)f2bf_bits(b[3]);
  return r;
}

// ---------- K1: degree + adjS = bf16(dnorm_row * adj) (r2, proven) ----------
// one wave per row; row held in 32 VGPR/lane: single read, single write
__global__ void k_degcvt(const float* __restrict__ adj, float* __restrict__ dnorm,
                         short* __restrict__ adjS) {
  const int wv = threadIdx.x >> 6;
  const int ln = threadIdx.x & 63;
  const int row = blockIdx.x * 4 + wv;  // 0..16383
  const f32x4* rowp = (const f32x4*)(adj + (size_t)row * NN);
  f32x4 v[8];
  float s = 0.0f;
#pragma unroll
  for (int i = 0; i < 8; ++i) {
    v[i] = rowp[i * 64 + ln];
    s += v[i][0] + v[i][1] + v[i][2] + v[i][3];
  }
#pragma unroll
  for (int off = 32; off >= 1; off >>= 1) s += __shfl_xor(s, off);
  const float dn = rsqrtf(s + 1e-8f);
  if (ln == 0) dnorm[row] = dn;
  u32x2* orow = (u32x2*)(adjS + (size_t)row * NN);
#pragma unroll
  for (int i = 0; i < 8; ++i) {
    u32x2 u;
    u[0] = (unsigned)f2bf_bits(v[i][0] * dn) | ((unsigned)f2bf_bits(v[i][1] * dn) << 16);
    u[1] = (unsigned)f2bf_bits(v[i][2] * dn) | ((unsigned)f2bf_bits(v[i][3] * dn) << 16);
    orow[i * 64 + ln] = u;
  }
}

// ---------- K2: yT[b][d][n] = bf16(dnorm[n] * (x@W)[n][d]) (proven) ----------
__global__ void k_y(const float* __restrict__ x, const float* __restrict__ W,
                    const float* __restrict__ dnorm, short* __restrict__ yT) {
  const int ln = threadIdx.x & 63;
  const int wv = threadIdx.x >> 6;
  const int bb = blockIdx.x >> 5;
  const int n0 = (blockIdx.x & 31) << 6;
  const int l15 = ln & 15, l4 = ln >> 4;
  const int dbase = wv * 32;

  short8 af[2][4];
#pragma unroll
  for (int dt = 0; dt < 2; ++dt)
#pragma unroll
    for (int ks = 0; ks < 4; ++ks) {
      short8 a;
#pragma unroll
      for (int j = 0; j < 8; ++j)
        a[j] = (short)f2bf_bits(W[(size_t)(ks * 32 + l4 * 8 + j) * DD + dbase + dt * 16 + l15]);
      af[dt][ks] = a;
    }

  f32x4 acc[2][4];
#pragma unroll
  for (int dt = 0; dt < 2; ++dt)
#pragma unroll
    for (int nt = 0; nt < 4; ++nt) acc[dt][nt] = (f32x4)0.0f;

  const float* xb = x + (size_t)bb * NN * DD;
  const float* dnb = dnorm + (size_t)bb * NN;
#pragma unroll
  for (int nt = 0; nt < 4; ++nt) {
    const int n = n0 + nt * 16 + l15;
    const float dn = dnb[n];
#pragma unroll
    for (int ks = 0; ks < 4; ++ks) {
      f32x4 p = *(const f32x4*)(xb + (size_t)n * DD + ks * 32 + l4 * 8);
      f32x4 q = *(const f32x4*)(xb + (size_t)n * DD + ks * 32 + l4 * 8 + 4);
      short8 bf = cvt8(p * dn, q * dn);
#pragma unroll
      for (int dt = 0; dt < 2; ++dt)
        acc[dt][nt] = __builtin_amdgcn_mfma_f32_16x16x32_bf16(af[dt][ks], bf, acc[dt][nt], 0, 0, 0);
    }
  }

  short* yb = yT + (size_t)bb * DD * NN;
#pragma unroll
  for (int dt = 0; dt < 2; ++dt)
#pragma unroll
    for (int nt = 0; nt < 4; ++nt)
#pragma unroll
      for (int rr = 0; rr < 4; ++rr) {
        int d = dbase + dt * 16 + l4 * 4 + rr;
        yb[(size_t)d * NN + n0 + nt * 16 + l15] = (short)f2bf_bits(acc[dt][nt][rr]);
      }
}

// ---------- K3: out = adjS @ y + b  (r7 structure, bf16 A) ----------
// BM=32, BK=64, 512 thr, grid 512 (2 blocks/CU). A depth-8 regs (u32x2),
// B depth-4; NBUF=4 LDS ring; one lgkmcnt(0)+barrier per K-tile. A-staging
// is a raw 8B bit-copy (adjS already bf16, dnorm_row folded).
__launch_bounds__(512, 4)
__global__ void k_gemmS(const short* __restrict__ adjS, const short* __restrict__ yT,
                        const float* __restrict__ bias, float* __restrict__ out) {
  __shared__ short As[4][2048];  // 4 x 4 KB: [32 rows][64 k] bf16, XOR-swizzled

  const int t = threadIdx.x;
  const int ln = t & 63;
  const int wv = t >> 6;
  const int orig = ((blockIdx.x & 7) << 6) | (blockIdx.x >> 3);  // XCD-bijective
  const int bb = orig >> 6;
  const int m0 = (orig & 63) << 5;

  const short* ablk = adjS + ((size_t)bb * NN + m0) * NN;
  const int oc = (wv << 4) + (ln & 15);
  const int kg8 = (ln >> 4) << 3;
  const short* ybase = yT + ((size_t)bb * DD + oc) * NN;

  const unsigned srow = (unsigned)t >> 4;        // 0..31
  const unsigned sc = ((unsigned)t & 15u) << 2;  // bf16 col (×4 shorts = 8B)

  f32x4 acc[2];
  acc[0] = (f32x4)0.0f; acc[1] = (f32x4)0.0f;

  auto loadA = [&](int tile) -> u32x2 {
    return *(const u32x2*)(ablk + (size_t)srow * NN + (tile << 6) + sc);
  };
  auto loadB = [&](int tile, int ks) -> short8 {
    return *(const short8*)(ybase + (tile << 6) + ks * 32 + kg8);
  };
  auto writeA = [&](u32x2 v, int buf) {
    unsigned byte = (srow << 7) + (sc << 1);
    byte ^= (srow & 7u) << 4;                    // closed within 128B row
    *(u32x2*)((char*)As + (buf << 12) + byte) = v;
  };
  auto compute = [&](int buf, short8 b0, short8 b1) {
    const char* base = (const char*)As + (buf << 12);
#pragma unroll
    for (int ks = 0; ks < 2; ++ks) {
      short8 bf = ks ? b1 : b0;
#pragma unroll
      for (int m = 0; m < 2; ++m) {
        unsigned row = (unsigned)(m * 16 + (ln & 15));
        unsigned byte = (row << 7) + (unsigned)((ks * 32 + kg8) << 1);
        byte ^= (row & 7u) << 4;
        short8 a = *(const short8*)(base + byte);
        acc[m] = __builtin_amdgcn_mfma_f32_16x16x32_bf16(a, bf, acc[m], 0, 0, 0);
      }
    }
  };

  // prologue: A tiles 0..7 in regs, B tiles 0..3 in regs, tile 0 -> buf0
  u32x2 sA0 = loadA(0), sA1 = loadA(1), sA2 = loadA(2), sA3 = loadA(3);
  u32x2 sA4 = loadA(4), sA5 = loadA(5), sA6 = loadA(6), sA7 = loadA(7);
  short8 b0k0 = loadB(0, 0), b0k1 = loadB(0, 1);
  short8 b1k0 = loadB(1, 0), b1k1 = loadB(1, 1);
  short8 b2k0 = loadB(2, 0), b2k1 = loadB(2, 1);
  short8 b3k0 = loadB(3, 0), b3k1 = loadB(3, 1);
  writeA(sA0, 0);
  asm volatile("s_waitcnt lgkmcnt(0)\n\ts_barrier" ::: "memory");

#define GITER(T, SNEW, SWR, BK0, BK1)                                   \
  {                                                                     \
    if ((T) < 24) SNEW = loadA((T) + 8);                                \
    short8 nb0 = BK0, nb1 = BK1;                                        \
    if ((T) < 28) { nb0 = loadB((T) + 4, 0); nb1 = loadB((T) + 4, 1); } \
    writeA(SWR, ((T) + 1) & 3);                                         \
    asm volatile("s_waitcnt lgkmcnt(0)\n\ts_barrier" ::: "memory");     \
    compute((T) & 3, BK0, BK1);                                         \
    BK0 = nb0; BK1 = nb1;                                               \
  }

#pragma unroll 1
  for (int t8 = 0; t8 < 32; t8 += 8) {
    GITER(t8 + 0, sA0, sA1, b0k0, b0k1);
    GITER(t8 + 1, sA1, sA2, b1k0, b1k1);
    GITER(t8 + 2, sA2, sA3, b2k0, b2k1);
    GITER(t8 + 3, sA3, sA4, b3k0, b3k1);
    GITER(t8 + 4, sA4, sA5, b0k0, b0k1);
    GITER(t8 + 5, sA5, sA6, b1k0, b1k1);
    GITER(t8 + 6, sA6, sA7, b2k0, b2k1);
    GITER(t8 + 7, sA7, sA0, b3k0, b3k1);
  }
#undef GITER

  // epilogue: dnorm_row folded into adjS; just bias + store
  const float bv = bias[oc];
  const int rbase = (ln >> 4) << 2;
#pragma unroll
  for (int m = 0; m < 2; ++m)
#pragma unroll
    for (int rr = 0; rr < 4; ++rr)
      out[(size_t)(bb * NN + m0 + m * 16 + rbase + rr) * DD + oc] = acc[m][rr] + bv;
}

extern "C" void kernel_launch(void* const* d_in, const int* in_sizes, int n_in,
                              void* d_out, int out_size, void* d_ws, size_t ws_size,
                              hipStream_t stream) {
  (void)in_sizes; (void)n_in; (void)out_size; (void)ws_size;
  const float* x = (const float*)d_in[0];
  const float* adj = (const float*)d_in[1];
  const float* W = (const float*)d_in[2];
  const float* bias = (const float*)d_in[3];
  float* out = (float*)d_out;

  char* ws = (char*)d_ws;
  float* dnorm = (float*)ws;                          // 64 KB
  short* yT = (short*)(ws + (1 << 16));               // 4 MB
  short* adjS = (short*)(ws + (1 << 16) + (4 << 20)); // 67 MB

  k_degcvt<<<4096, 256, 0, stream>>>(adj, dnorm, adjS);
  k_y<<<256, 256, 0, stream>>>(x, W, dnorm, yT);
  k_gemmS<<<512, 512, 0, stream>>>(adjS, yT, bias, out);
}

// Round 12
// 67.932 us; speedup vs baseline: 1.9516x; 1.1366x over previous
//
#include <hip/hip_runtime.h>
#include <hip/hip_bf16.h>

#define NN 2048
#define DD 128

typedef __attribute__((ext_vector_type(4))) float f32x4;
typedef __attribute__((ext_vector_type(8))) short short8;

__device__ __forceinline__ unsigned short f2bf_bits(float f) {
  union { __hip_bfloat16 h; unsigned short s; } u;
  u.h = __float2bfloat16(f);
  return u.s;
}

__device__ __forceinline__ short8 cvt8(f32x4 a, f32x4 b) {
  short8 r;
  r[0] = (short)f2bf_bits(a[0]); r[1] = (short)f2bf_bits(a[1]);
  r[2] = (short)f2bf_bits(a[2]); r[3] = (short)f2bf_bits(a[3]);
  r[4] = (short)f2bf_bits(b[0]); r[5] = (short)f2bf_bits(b[1]);
  r[6] = (short)f2bf_bits(b[2]); r[7] = (short)f2bf_bits(b[3]);
  return r;
}

__device__ __forceinline__ void gld16(const void* src, void* lds) {
  __builtin_amdgcn_global_load_lds(
      (const __attribute__((address_space(1))) void*)src,
      (__attribute__((address_space(3))) void*)lds, 16, 0, 0);
}

// ---------- K1: dnorm = rsqrt(rowsum(adj)+1e-8) (pure read, ~21 µs) ----------
__global__ void k_degree(const float* __restrict__ adj, float* __restrict__ dnorm) {
  const int wv = threadIdx.x >> 6;
  const int ln = threadIdx.x & 63;
  const int row = blockIdx.x * 4 + wv;
  const f32x4* rowp = (const f32x4*)(adj + (size_t)row * NN);
  float s = 0.0f;
#pragma unroll
  for (int i = 0; i < 8; ++i) {
    f32x4 v = rowp[i * 64 + ln];
    s += v[0] + v[1] + v[2] + v[3];
  }
#pragma unroll
  for (int off = 32; off >= 1; off >>= 1) s += __shfl_xor(s, off);
  if (ln == 0) dnorm[row] = rsqrtf(s + 1e-8f);
}

// ---------- K2: yT[b][d][n] = bf16(dnorm[n] * (x@W)[n][d]) (proven) ----------
__global__ void k_y(const float* __restrict__ x, const float* __restrict__ W,
                    const float* __restrict__ dnorm, short* __restrict__ yT) {
  const int ln = threadIdx.x & 63;
  const int wv = threadIdx.x >> 6;
  const int bb = blockIdx.x >> 5;
  const int n0 = (blockIdx.x & 31) << 6;
  const int l15 = ln & 15, l4 = ln >> 4;
  const int dbase = wv * 32;

  short8 af[2][4];
#pragma unroll
  for (int dt = 0; dt < 2; ++dt)
#pragma unroll
    for (int ks = 0; ks < 4; ++ks) {
      short8 a;
#pragma unroll
      for (int j = 0; j < 8; ++j)
        a[j] = (short)f2bf_bits(W[(size_t)(ks * 32 + l4 * 8 + j) * DD + dbase + dt * 16 + l15]);
      af[dt][ks] = a;
    }

  f32x4 acc[2][4];
#pragma unroll
  for (int dt = 0; dt < 2; ++dt)
#pragma unroll
    for (int nt = 0; nt < 4; ++nt) acc[dt][nt] = (f32x4)0.0f;

  const float* xb = x + (size_t)bb * NN * DD;
  const float* dnb = dnorm + (size_t)bb * NN;
#pragma unroll
  for (int nt = 0; nt < 4; ++nt) {
    const int n = n0 + nt * 16 + l15;
    const float dn = dnb[n];
#pragma unroll
    for (int ks = 0; ks < 4; ++ks) {
      f32x4 p = *(const f32x4*)(xb + (size_t)n * DD + ks * 32 + l4 * 8);
      f32x4 q = *(const f32x4*)(xb + (size_t)n * DD + ks * 32 + l4 * 8 + 4);
      short8 bf = cvt8(p * dn, q * dn);
#pragma unroll
      for (int dt = 0; dt < 2; ++dt)
        acc[dt][nt] = __builtin_amdgcn_mfma_f32_16x16x32_bf16(af[dt][ks], bf, acc[dt][nt], 0, 0, 0);
    }
  }

  short* yb = yT + (size_t)bb * DD * NN;
#pragma unroll
  for (int dt = 0; dt < 2; ++dt)
#pragma unroll
    for (int nt = 0; nt < 4; ++nt)
#pragma unroll
      for (int rr = 0; rr < 4; ++rr) {
        int d = dbase + dt * 16 + l4 * 4 + rr;
        yb[(size_t)d * NN + n0 + nt * 16 + l15] = (short)f2bf_bits(acc[dt][nt][rr]);
      }
}

// ---------- K3: out = dnorm_row * (adj @ y) + b ----------
// r2's counted-vmcnt structure (best GEMM measured, ~31 µs on bf16 A),
// ported to f32 A: BM=64, BK=64, 512 thr, grid 256 (1 blk/CU). A staged
// 5 tiles ahead via gld_lds width-16 into 6 x 16 KB f32 LDS bufs
// (pre-swizzled src, linear dest, swizzled read — rule #21); f32->bf16
// cvt in-register at MFMA time. B depth-2 regs from L2. vmcnt(12), never
// drained in-loop (T4). dnorm_row applied in f32 epilogue.
__launch_bounds__(512, 1)
__global__ void k_gemm2(const float* __restrict__ adj, const short* __restrict__ yT,
                        const float* __restrict__ dnorm, const float* __restrict__ bias,
                        float* __restrict__ out) {
  __shared__ float As[6][4096];  // 6 x 16 KB: [64 rows][64 k] f32, 256 B rows

  const int t = threadIdx.x;
  const int ln = t & 63;
  const int wv = t >> 6;
  const int orig = ((blockIdx.x & 7) << 5) | (blockIdx.x >> 3);  // XCD-bijective, 256
  const int bb = orig >> 5;
  const int m0 = (orig & 31) << 6;

  const char* ablk = (const char*)(adj + ((size_t)bb * NN + m0) * NN);
  const int oc = (wv << 4) + (ln & 15);
  const int kg8 = (ln >> 4) << 3;
  const short* ybase = yT + ((size_t)bb * DD + oc) * NN;

  f32x4 acc[4];
#pragma unroll
  for (int m = 0; m < 4; ++m) acc[m] = (f32x4)0.0f;

  auto stage = [&](int tile, int buf) {
#pragma unroll
    for (int j = 0; j < 2; ++j) {
      unsigned L = ((unsigned)j << 13) + ((unsigned)t << 4);  // 0..16368
      unsigned row = L >> 8;
      unsigned off = L & 255u;
      unsigned soff = off ^ ((row & 7u) << 4);
      const char* src = ablk + (size_t)row * (NN * 4) + (size_t)tile * 256 + soff;
      gld16(src, (char*)As + buf * 16384 + L);
    }
  };
  auto loadB = [&](int tile, int ks) -> short8 {
    return *(const short8*)(ybase + ((tile & 31) << 6) + ks * 32 + kg8);
  };
  auto compute = [&](int buf, short8 b0, short8 b1) {
    const char* base = (const char*)As + buf * 16384;
#pragma unroll
    for (int ks = 0; ks < 2; ++ks) {
      short8 bf = ks ? b1 : b0;
#pragma unroll
      for (int m = 0; m < 4; ++m) {
        unsigned row = (unsigned)(m * 16 + (ln & 15));
        unsigned c = (unsigned)(ks * 128 + (ln >> 4) * 32);
        unsigned sw = (row & 7u) << 4;
        f32x4 f0 = *(const f32x4*)(base + (row << 8) + (c ^ sw));
        f32x4 f1 = *(const f32x4*)(base + (row << 8) + ((c + 16) ^ sw));
        acc[m] = __builtin_amdgcn_mfma_f32_16x16x32_bf16(cvt8(f0, f1), bf, acc[m], 0, 0, 0);
      }
    }
  };

  // prologue: tiles 0..4 staged, B(0),B(1) in regs, full drain, barrier
#pragma unroll
  for (int p = 0; p < 5; ++p) stage(p, p);
  short8 b0k0 = loadB(0, 0), b0k1 = loadB(0, 1);
  short8 b1k0 = loadB(1, 0), b1k1 = loadB(1, 1);
  asm volatile("s_waitcnt vmcnt(0)\n\ts_barrier" ::: "memory");

  int cbuf = 0, sbuf = 5;
#pragma unroll 1
  for (int tt = 0; tt < 32; tt += 2) {
    // even half-iter: tile tt
    if (tt + 5 < 32) stage(tt + 5, sbuf);
    short8 n0k0 = loadB(tt + 2, 0), n0k1 = loadB(tt + 2, 1);
    compute(cbuf, b0k0, b0k1);
    asm volatile("s_waitcnt vmcnt(12)\n\ts_barrier" ::: "memory");
    cbuf = (cbuf == 5) ? 0 : cbuf + 1;
    sbuf = (sbuf == 5) ? 0 : sbuf + 1;
    // odd half-iter: tile tt+1
    if (tt + 6 < 32) stage(tt + 6, sbuf);
    short8 n1k0 = loadB(tt + 3, 0), n1k1 = loadB(tt + 3, 1);
    compute(cbuf, b1k0, b1k1);
    asm volatile("s_waitcnt vmcnt(12)\n\ts_barrier" ::: "memory");
    cbuf = (cbuf == 5) ? 0 : cbuf + 1;
    sbuf = (sbuf == 5) ? 0 : sbuf + 1;
    b0k0 = n0k0; b0k1 = n0k1; b1k0 = n1k0; b1k1 = n1k1;
  }

  // epilogue: out = dnorm_row * acc + bias
  const float bv = bias[oc];
  const int rbase = (ln >> 4) << 2;
#pragma unroll
  for (int m = 0; m < 4; ++m) {
    f32x4 dn = *(const f32x4*)(dnorm + (size_t)bb * NN + m0 + m * 16 + rbase);
#pragma unroll
    for (int rr = 0; rr < 4; ++rr)
      out[(size_t)(bb * NN + m0 + m * 16 + rbase + rr) * DD + oc] = acc[m][rr] * dn[rr] + bv;
  }
}

extern "C" void kernel_launch(void* const* d_in, const int* in_sizes, int n_in,
                              void* d_out, int out_size, void* d_ws, size_t ws_size,
                              hipStream_t stream) {
  (void)in_sizes; (void)n_in; (void)out_size; (void)ws_size;
  const float* x = (const float*)d_in[0];
  const float* adj = (const float*)d_in[1];
  const float* W = (const float*)d_in[2];
  const float* bias = (const float*)d_in[3];
  float* out = (float*)d_out;

  char* ws = (char*)d_ws;
  float* dnorm = (float*)ws;             // 64 KB
  short* yT = (short*)(ws + (1 << 16));  // 4 MB

  k_degree<<<4096, 256, 0, stream>>>(adj, dnorm);
  k_y<<<256, 256, 0, stream>>>(x, W, dnorm, yT);
  k_gemm2<<<256, 512, 0, stream>>>(adj, yT, dnorm, bias, out);
}